// Round 15
// baseline (172.651 us; speedup 1.0000x reference)
//
#include <hip/hip_runtime.h>
#include <math.h>
#include <stdint.h>

// YOLOv2 loss: pred/target (16,52,52,5,85) fp32 -> scalar fp32.
// Fused kernel, 512-thread block owns 32 cells end-to-end:
//   - threads 0..159 decode PRED anchors, threads 256..415 decode TARGET
//     anchors IN PARALLEL (disjoint waves) -> LDS
//   - lanes 0..31 of wave 0: greedy IoU matching + box/obj losses
//   - 32 groups x 16 lanes: class NLL, 5 slots per group (halved chain)
//   - block partial -> part_ws; reduce kernel sums 1352 partials.
// 8 waves/block x 4 resident blocks/CU = 32 waves/CU (100% occupancy cap).

#define NIMG   16
#define NA     5
#define STRIDE 85                    // 5+80 floats per anchor
#define CELLF  (NA * STRIDE)         // 425
#define NCELLS 43264                 // 16*52*52
#define CPB    32                    // cells per block
#define BT     512                   // threads per block (8 waves)
#define NANCHB (CPB * NA)            // 160 anchors per block
#define NB     (NCELLS / CPB)        // 1352 blocks

__device__ __constant__ float AW[5] = {0.57273f, 1.87446f, 3.33843f, 7.88282f, 9.77052f};
__device__ __constant__ float AH[5] = {0.677385f, 2.06253f, 5.47434f, 3.52778f, 9.16828f};

__device__ inline float softplusf(float x) {
    return fmaxf(x, 0.0f) + log1pf(expf(-fabsf(x)));
}
__device__ inline float sigmoidf(float x) { return 1.0f / (1.0f + expf(-x)); }

__global__ __launch_bounds__(BT) void yolo_fused(
    const float* __restrict__ pred, const float* __restrict__ target,
    float* __restrict__ part_ws) {
    __shared__ float s_px1[NANCHB], s_px2[NANCHB], s_py1[NANCHB], s_py2[NANCHB], s_pA[NANCHB];
    __shared__ float s_gx1[NANCHB], s_gx2[NANCHB], s_gy1[NANCHB], s_gy2[NANCHB], s_gA[NANCHB];
    __shared__ float s_gobj[NANCHB];
    __shared__ float s_sx[NANCHB], s_sy[NANCHB], s_ptw[NANCHB], s_pth[NANCHB];
    __shared__ float s_spn[NANCHB], s_spp[NANCHB];
    __shared__ float s_tx[NANCHB], s_ty[NANCHB], s_tw[NANCHB], s_th[NANCHB];
    __shared__ uint32_t s_assign[CPB];
    __shared__ float s_wpart[BT / 64];

    const int t = threadIdx.x;

    // ---- decode: pred on threads 0..159, target on threads 256..415 (parallel waves)
    if (t < NANCHB) {
        const int ga = blockIdx.x * NANCHB + t;
        const int a = t % NA;
        const float* pa = pred + (size_t)ga * STRIDE;
        const float p0 = pa[0], p1 = pa[1], p2 = pa[2], p3 = pa[3], p4 = pa[4];
        const float aw = AW[a], ah = AH[a];
        const float sx = sigmoidf(p0);
        const float sy = sigmoidf(p1);
        const float pw = expf(p2) * aw, ph = expf(p3) * ah;
        s_px1[t] = sx - pw * 0.5f;  s_px2[t] = sx + pw * 0.5f;
        s_py1[t] = sy - ph * 0.5f;  s_py2[t] = sy + ph * 0.5f;
        s_pA[t]  = pw * ph;
        s_sx[t] = sx;  s_sy[t] = sy;  s_ptw[t] = p2;  s_pth[t] = p3;
        s_spn[t] = softplusf(-p4);    s_spp[t] = softplusf(p4);
    } else if (t >= 256 && t < 256 + NANCHB) {
        const int u = t - 256;
        const int ga = blockIdx.x * NANCHB + u;
        const int a = u % NA;
        const float* ta = target + (size_t)ga * STRIDE;
        const float t0 = ta[0], t1 = ta[1], t2 = ta[2], t3 = ta[3], t4 = ta[4];
        const float aw = AW[a], ah = AH[a];
        const float gw = expf(t2) * aw, gh = expf(t3) * ah;
        s_gx1[u] = t0 - gw * 0.5f;  s_gx2[u] = t0 + gw * 0.5f;
        s_gy1[u] = t1 - gh * 0.5f;  s_gy2[u] = t1 + gh * 0.5f;
        s_gA[u]  = gw * gh;
        s_gobj[u] = t4;
        s_tx[u] = t0;  s_ty[u] = t1;  s_tw[u] = t2;  s_th[u] = t3;
    }
    __syncthreads();

    // ---- matching + box/obj losses: lane-per-cell (threads 0..31) ----
    float loss = 0.0f;
    if (t < CPB) {
        const int la = t * NA;                          // stride 5: conflict-free mod 32
        float iou[NA][NA];
#pragma unroll
        for (int g = 0; g < NA; ++g) {
            const float gx1 = s_gx1[la+g], gx2 = s_gx2[la+g];
            const float gy1 = s_gy1[la+g], gy2 = s_gy2[la+g];
            const float gA  = s_gA[la+g];
#pragma unroll
            for (int p = 0; p < NA; ++p) {
                float iw = fmaxf(fminf(gx2, s_px2[la+p]) - fmaxf(gx1, s_px1[la+p]), 0.0f);
                float ih = fmaxf(fminf(gy2, s_py2[la+p]) - fmaxf(gy1, s_py1[la+p]), 0.0f);
                float inter = iw * ih;
                iou[g][p] = inter / (gA + s_pA[la+p] - inter + 1e-9f);
            }
        }
        int assign[NA] = {-1, -1, -1, -1, -1};
        bool taken[NA] = {false, false, false, false, false};
#pragma unroll
        for (int g = 0; g < NA; ++g) {
            if (s_gobj[la+g] > 0.5f) {
                float best = -2.0f; int bi = 0;
#pragma unroll
                for (int p = 0; p < NA; ++p) {
                    float v = taken[p] ? -1.0f : iou[g][p];
                    if (v > best) { best = v; bi = p; }
                }
                taken[bi] = true;
                assign[bi] = g;
            }
        }
        uint32_t word = 0;
        float l_xy = 0.f, l_wh = 0.f, l_obj = 0.f, l_noobj = 0.f;
#pragma unroll
        for (int p = 0; p < NA; ++p) {
            const int g = assign[p];
            word |= (uint32_t)(g + 1) << (4 * p);
            if (g >= 0) {
                float dx = s_sx[la+p] - s_tx[la+g];
                float dy = s_sy[la+p] - s_ty[la+g];
                l_xy += dx * dx + dy * dy;
                float dw = s_ptw[la+p] - s_tw[la+g];
                float dh = s_pth[la+p] - s_th[la+g];
                l_wh += dw * dw + dh * dh;
                l_obj += s_spn[la+p];
            } else {
                l_noobj += s_spp[la+p];
            }
        }
        s_assign[t] = word;
        loss = 5.0f * l_xy + 5.0f * l_wh + 1.0f * l_obj + 0.5f * l_noobj;
    }
    __syncthreads();

    // ---- class NLL: 32 groups x 16 lanes; 5 slots per group ----
    const int grp = t >> 4;
    const int ln  = t & 15;
#pragma unroll
    for (int si = 0; si < 5; ++si) {
        const int slot = grp * 5 + si;                  // 0..159
        const int cell = slot / NA;
        const int p    = slot - cell * NA;
        const int g    = (int)((s_assign[cell] >> (4 * p)) & 0xFu) - 1;
        if (g >= 0) {                                   // uniform across the 16-lane group
            const size_t cbase = ((size_t)blockIdx.x * CPB + cell) * CELLF;
            const float* pc = pred   + cbase + p * STRIDE + 5;
            const float* tc = target + cbase + g * STRIDE + 5;
            float pv[5], tv[5];
#pragma unroll
            for (int k = 0; k < 5; ++k) {
                pv[k] = pc[ln + 16 * k];
                tv[k] = tc[ln + 16 * k];
            }
            float m = fmaxf(fmaxf(fmaxf(pv[0], pv[1]), fmaxf(pv[2], pv[3])), pv[4]);
#pragma unroll
            for (int o = 1; o < 16; o <<= 1) m = fmaxf(m, __shfl_xor(m, o));
            float s = 0.f;
#pragma unroll
            for (int k = 0; k < 5; ++k) s += expf(pv[k] - m);
#pragma unroll
            for (int o = 1; o < 16; o <<= 1) s += __shfl_xor(s, o);
            float lse = m + logf(s);

            float bt = tv[0]; int bi = ln; float bp = pv[0];
#pragma unroll
            for (int k = 1; k < 5; ++k) {
                if (tv[k] > bt) { bt = tv[k]; bi = ln + 16 * k; bp = pv[k]; }
            }
#pragma unroll
            for (int o = 1; o < 16; o <<= 1) {
                float ot = __shfl_xor(bt, o);
                int   oi = __shfl_xor(bi, o);
                float op = __shfl_xor(bp, o);
                if (ot > bt || (ot == bt && oi < bi)) { bt = ot; bi = oi; bp = op; }
            }
            if (ln == 0) loss += lse - bp;              // L_CLS = 1.0
        }
    }

    // ---- block reduction: wave shuffle -> LDS -> thread 0 ----
#pragma unroll
    for (int o = 32; o; o >>= 1) loss += __shfl_xor(loss, o);
    if ((t & 63) == 0) s_wpart[t >> 6] = loss;
    __syncthreads();
    if (t == 0) {
        float b = 0.f;
#pragma unroll
        for (int w = 0; w < BT / 64; ++w) b += s_wpart[w];
        part_ws[blockIdx.x] = b;
    }
}

// ---- final reduction: one block over NB partials ----
__global__ __launch_bounds__(256) void yolo_reduce(
    const float* __restrict__ part_ws, float* __restrict__ out) {
    __shared__ float ws4[4];
    float s = 0.0f;
    for (int i = threadIdx.x; i < NB; i += 256) s += part_ws[i];
#pragma unroll
    for (int o = 32; o; o >>= 1) s += __shfl_xor(s, o);
    if ((threadIdx.x & 63) == 0) ws4[threadIdx.x >> 6] = s;
    __syncthreads();
    if (threadIdx.x == 0)
        out[0] = (ws4[0] + ws4[1] + ws4[2] + ws4[3]) * (1.0f / (float)NIMG);
}

extern "C" void kernel_launch(void* const* d_in, const int* in_sizes, int n_in,
                              void* d_out, int out_size, void* d_ws, size_t ws_size,
                              hipStream_t stream) {
    const float* pred   = (const float*)d_in[0];
    const float* target = (const float*)d_in[1];
    float* out = (float*)d_out;
    float* part_ws = (float*)d_ws;                     // NB floats (5.4 KB)

    yolo_fused<<<NB, BT, 0, stream>>>(pred, target, part_ws);
    yolo_reduce<<<1, 256, 0, stream>>>(part_ws, out);
}